// Round 3
// baseline (555.685 us; speedup 1.0000x reference)
//
#include <hip/hip_runtime.h>

// SpecCnn1d: y[b,o,f] = relu( sum_k x[b, o+k] * w[f,k] ), stride 1
// B=64, L=16384, F=128, K=16, out_len = L-K+1 = 16369
// Output 536 MB fp32 -> HBM write-bound. Conv write roofline ~86 us; the
// timed region also contains a ~347 us poison-fill (2.1 GB).
//
// v4 (after v1/v2/v3 post-mortem): conv stuck at ~196-200 us across three
// store widths and with/without prefetch -> neither store width nor load
// latency is the limiter. Untested axis: STREAM STRUCTURE. v1-v3 used 16384
// one-shot blocks writing 32 KB each (~16 sequential residency generations
// per CU, weight reload each time, chopped store bursts). The 6.2 TB/s fill
// kernel is the opposite: few persistent waves, long contiguous sweeps.
// v4: ONE residency generation - 2048 blocks x 4 waves = 8192 waves
// = 256 CU x 32 waves exactly. Each wave owns one (b, 128-o strip):
// 64 KB contiguous store run, weights loaded once, ping-pong wave-uniform
// scalar x loads (the one thing that measurably mattered).

constexpr int K_TAPS  = 16;
constexpr int F_FILT  = 128;
constexpr int O_STRIP = 128;   // o positions per wave
constexpr int O_CHUNK = 8;     // o positions per compute burst
constexpr int WPB     = 4;     // waves per block
constexpr int NTHREAD = 64 * WPB;
constexpr int XS_N    = O_CHUNK + K_TAPS;   // 24 (need 23; 24 = 6 x float4)

__global__ __launch_bounds__(NTHREAD) void SpecCnn1d_conv_kernel(
    const float* __restrict__ x,     // [B, L]
    const float* __restrict__ w,     // [F, K]
    float* __restrict__ y,           // [B, out_len, F]
    int L, int out_len, int strips_per_b, int total_waves)
{
    const int lane = threadIdx.x & 63;
    const int gw   = blockIdx.x * WPB + (threadIdx.x >> 6);  // global wave id
    if (gw >= total_waves) return;
    const int b    = gw / strips_per_b;
    const int s0   = (gw - b * strips_per_b) * O_STRIP;      // strip start o
    const int f    = lane << 1;                              // filters f, f+1

    // Weight pair -> 32 VGPRs. Lane reads 128 contiguous bytes at f*64:
    // wave covers the whole 8 KB w, fully coalesced, L2-hot after wave 0.
    float w0[K_TAPS], w1[K_TAPS];
    {
        const float4* wp = reinterpret_cast<const float4*>(w + (size_t)f * K_TAPS);
        #pragma unroll
        for (int i = 0; i < K_TAPS / 4; ++i) {
            float4 v0 = wp[i];          // row f
            float4 v1 = wp[i + 4];      // row f+1
            w0[4*i+0] = v0.x; w0[4*i+1] = v0.y; w0[4*i+2] = v0.z; w0[4*i+3] = v0.w;
            w1[4*i+0] = v1.x; w1[4*i+1] = v1.y; w1[4*i+2] = v1.z; w1[4*i+3] = v1.w;
        }
    }

    const float* xb = x + (size_t)b * L;
    // float2 view: row stride between o's is F_FILT/2 = 64 float2.
    float2* yb = reinterpret_cast<float2*>(y + ((size_t)b * out_len + s0) * F_FILT) + lane;

    if (s0 + O_STRIP + K_TAPS <= L && s0 + O_STRIP <= out_len) {
        // Fast path (all strips except the last one per b): reads and stores
        // unguarded.
        float xs0[XS_N], xs1[XS_N];

        // Wave-uniform window load: address has NO threadIdx dependence ->
        // scalar loads (SGPRs, SMEM pipe, no VMEM).
        auto LOADU = [&](float* xs, int oc) {
            const float4* xp = reinterpret_cast<const float4*>(xb + s0 + oc);
            #pragma unroll
            for (int i = 0; i < XS_N / 4; ++i) {
                float4 v = xp[i];
                xs[4*i+0] = v.x; xs[4*i+1] = v.y; xs[4*i+2] = v.z; xs[4*i+3] = v.w;
            }
        };
        // 8 outputs: 256 FMAs (2 filters x 16 taps x 8 o) + 8 float2 stores.
        auto COMP = [&](const float* xs, int oc) {
            #pragma unroll
            for (int oo = 0; oo < O_CHUNK; ++oo) {
                float a0 = 0.0f, a1 = 0.0f;
                #pragma unroll
                for (int k = 0; k < K_TAPS; ++k) {
                    const float xv = xs[oo + k];
                    a0 = fmaf(xv, w0[k], a0);
                    a1 = fmaf(xv, w1[k], a1);
                }
                float2 r;
                r.x = fmaxf(a0, 0.0f);
                r.y = fmaxf(a1, 0.0f);
                yb[(size_t)(oc + oo) * (F_FILT / 2)] = r;
            }
        };

        LOADU(xs0, 0);
        #pragma unroll
        for (int oc = 0; oc < O_STRIP; oc += 2 * O_CHUNK) {
            LOADU(xs1, oc + O_CHUNK);        // prefetch next window
            COMP(xs0, oc);                   // compute under the loads
            if (oc + 2 * O_CHUNK < O_STRIP)
                LOADU(xs0, oc + 2 * O_CHUNK);
            COMP(xs1, oc + O_CHUNK);
        }
    } else {
        // Tail strip (last strip of each b): clamp reads into bounds
        // (clamped values only feed o >= out_len, never stored), guard stores.
        for (int oc = 0; oc < O_STRIP; oc += O_CHUNK) {
            const int base = s0 + oc;
            if (base >= out_len) break;
            float xs[XS_N];
            #pragma unroll
            for (int j = 0; j < XS_N; ++j) {
                int xi = base + j;
                xi = (xi < L) ? xi : (L - 1);
                xs[j] = xb[xi];
            }
            #pragma unroll
            for (int oo = 0; oo < O_CHUNK; ++oo) {
                float a0 = 0.0f, a1 = 0.0f;
                #pragma unroll
                for (int k = 0; k < K_TAPS; ++k) {
                    const float xv = xs[oo + k];
                    a0 = fmaf(xv, w0[k], a0);
                    a1 = fmaf(xv, w1[k], a1);
                }
                float2 r;
                r.x = fmaxf(a0, 0.0f);
                r.y = fmaxf(a1, 0.0f);
                if (base + oo < out_len)
                    yb[(size_t)(oc + oo) * (F_FILT / 2)] = r;
            }
        }
    }
}

extern "C" void kernel_launch(void* const* d_in, const int* in_sizes, int n_in,
                              void* d_out, int out_size, void* d_ws, size_t ws_size,
                              hipStream_t stream) {
    const float* x = (const float*)d_in[0];   // 64*16384 fp32
    const float* w = (const float*)d_in[1];   // 128*16  fp32
    float*       y = (float*)d_out;           // 64*16369*128 fp32

    const int B = 64;
    const int L = in_sizes[0] / B;            // 16384
    const int out_len = L - K_TAPS + 1;       // 16369

    const int strips_per_b = (out_len + O_STRIP - 1) / O_STRIP;  // 128
    const int total_waves  = B * strips_per_b;                   // 8192
    const int grid_blocks  = (total_waves + WPB - 1) / WPB;      // 2048

    dim3 grid(grid_blocks);
    dim3 block(NTHREAD);
    SpecCnn1d_conv_kernel<<<grid, block, 0, stream>>>(
        x, w, y, L, out_len, strips_per_b, total_waves);
}

// Round 5
// 538.961 us; speedup vs baseline: 1.0310x; 1.0310x over previous
//
#include <hip/hip_runtime.h>

// SpecCnn1d: y[b,o,f] = relu( sum_k x[b, o+k] * w[f,k] ), stride 1
// B=64, L=16384, F=128, K=16, out_len = L-K+1 = 16369
// Output 536 MB fp32 -> HBM write-bound. Conv write roofline ~86 us; the
// timed region also contains a ~347 us poison-fill (2.1 GB).
//
// v5b (compile fix of v5): __builtin_nontemporal_store requires a clang
// ext_vector type, not HIP's float2 struct. Theory unchanged (v1-v4
// post-mortem): conv flat at ~196-210 us across four structures ->
// structure-insensitive; remaining quantitative fit is WRITE-ALLOCATE (RFO):
// store-miss line allocation makes the output stream cost read 536 MB +
// write 536 MB = 1.07 GB -> ~170 us at 6.3 TB/s + ~30 us VALU = observed
// ~200 us. The fill kernel's FETCH_SIZE ~8 KB shows it uses a
// non-allocating path and hits 6.2 TB/s on the same buffer.
// v5b = v3 with all output stores as nontemporal (nt) dwordx2.

constexpr int K_TAPS  = 16;
constexpr int F_FILT  = 128;
constexpr int O_TILE  = 64;    // o positions per block (one wave)
constexpr int O_CHUNK = 8;     // o positions per compute burst
constexpr int NTHREAD = 64;    // one wave; lane covers filters 2l, 2l+1
constexpr int XS_N    = O_CHUNK + K_TAPS;  // 24 (need 23; 24 = 6 x float4)

typedef float f32x2 __attribute__((ext_vector_type(2)));

__global__ __launch_bounds__(NTHREAD) void SpecCnn1d_conv_kernel(
    const float* __restrict__ x,     // [B, L]
    const float* __restrict__ w,     // [F, K]
    float* __restrict__ y,           // [B, out_len, F]
    int L, int out_len)
{
    const int lane = threadIdx.x;        // 0..63
    const int f    = lane << 1;          // filter pair 2l, 2l+1
    const int b    = blockIdx.y;
    const int o0   = blockIdx.x * O_TILE;

    // Weight pair -> 32 VGPRs. Lane reads 128 contiguous bytes at f*64:
    // wave covers the whole 8 KB w, fully coalesced, L2-hot after block 0.
    float w0[K_TAPS], w1[K_TAPS];
    {
        const float4* wp = reinterpret_cast<const float4*>(w + (size_t)f * K_TAPS);
        #pragma unroll
        for (int i = 0; i < K_TAPS / 4; ++i) {
            float4 v0 = wp[i];          // row f
            float4 v1 = wp[i + 4];      // row f+1
            w0[4*i+0] = v0.x; w0[4*i+1] = v0.y; w0[4*i+2] = v0.z; w0[4*i+3] = v0.w;
            w1[4*i+0] = v1.x; w1[4*i+1] = v1.y; w1[4*i+2] = v1.z; w1[4*i+3] = v1.w;
        }
    }

    const float* xb = x + (size_t)b * L;
    // f32x2 view: row stride between o's is F_FILT/2 = 64 elements.
    f32x2* yb = reinterpret_cast<f32x2*>(y + ((size_t)b * out_len + o0) * F_FILT) + lane;

    // Fast path: every read (up to o0+79) and every store (o < o0+64) in
    // bounds. True for all blockIdx.x <= 254; only the last block tails.
    if (o0 + O_TILE + K_TAPS <= L) {
        float xs0[XS_N], xs1[XS_N];

        // Wave-uniform window load: address has NO threadIdx dependence ->
        // scalar loads (SGPRs, SMEM pipe, no VMEM).
        auto LOADU = [&](float* xs, int oc) {
            const float4* xp = reinterpret_cast<const float4*>(xb + o0 + oc);
            #pragma unroll
            for (int i = 0; i < XS_N / 4; ++i) {
                float4 v = xp[i];
                xs[4*i+0] = v.x; xs[4*i+1] = v.y; xs[4*i+2] = v.z; xs[4*i+3] = v.w;
            }
        };
        // 8 outputs: 256 FMAs (2 filters x 16 taps x 8 o) + 8 nt dwordx2 stores.
        auto COMP = [&](const float* xs, int oc) {
            #pragma unroll
            for (int oo = 0; oo < O_CHUNK; ++oo) {
                float a0 = 0.0f, a1 = 0.0f;
                #pragma unroll
                for (int k = 0; k < K_TAPS; ++k) {
                    const float xv = xs[oo + k];   // SGPR operand
                    a0 = fmaf(xv, w0[k], a0);
                    a1 = fmaf(xv, w1[k], a1);
                }
                f32x2 r;
                r.x = fmaxf(a0, 0.0f);
                r.y = fmaxf(a1, 0.0f);
                __builtin_nontemporal_store(r, yb + (size_t)(oc + oo) * (F_FILT / 2));
            }
        };

        LOADU(xs0, 0);
        #pragma unroll
        for (int oc = 0; oc < O_TILE; oc += 2 * O_CHUNK) {
            LOADU(xs1, oc + O_CHUNK);        // prefetch next window
            COMP(xs0, oc);                   // compute under the loads
            if (oc + 2 * O_CHUNK < O_TILE)
                LOADU(xs0, oc + 2 * O_CHUNK);
            COMP(xs1, oc + O_CHUNK);
        }
    } else {
        // Tail block (blockIdx.x == 255): clamp reads (clamped values only
        // feed o >= out_len, never stored), guard stores.
        for (int oc = 0; oc < O_TILE; oc += O_CHUNK) {
            const int base = o0 + oc;
            float xs[XS_N];
            #pragma unroll
            for (int j = 0; j < XS_N; ++j) {
                int xi = base + j;
                xi = (xi < L) ? xi : (L - 1);
                xs[j] = xb[xi];
            }
            #pragma unroll
            for (int oo = 0; oo < O_CHUNK; ++oo) {
                float a0 = 0.0f, a1 = 0.0f;
                #pragma unroll
                for (int k = 0; k < K_TAPS; ++k) {
                    const float xv = xs[oo + k];
                    a0 = fmaf(xv, w0[k], a0);
                    a1 = fmaf(xv, w1[k], a1);
                }
                f32x2 r;
                r.x = fmaxf(a0, 0.0f);
                r.y = fmaxf(a1, 0.0f);
                if (base + oo < out_len)
                    __builtin_nontemporal_store(r, yb + (size_t)(oc + oo) * (F_FILT / 2));
            }
        }
    }
}

extern "C" void kernel_launch(void* const* d_in, const int* in_sizes, int n_in,
                              void* d_out, int out_size, void* d_ws, size_t ws_size,
                              hipStream_t stream) {
    const float* x = (const float*)d_in[0];   // 64*16384 fp32
    const float* w = (const float*)d_in[1];   // 128*16  fp32
    float*       y = (float*)d_out;           // 64*16369*128 fp32

    const int B = 64;
    const int L = in_sizes[0] / B;            // 16384
    const int out_len = L - K_TAPS + 1;       // 16369

    dim3 grid((out_len + O_TILE - 1) / O_TILE, B);
    dim3 block(NTHREAD);
    SpecCnn1d_conv_kernel<<<grid, block, 0, stream>>>(x, w, y, L, out_len);
}